// Round 16
// baseline (109128.186 us; speedup 1.0000x reference)
//
#include <hip/hip_runtime.h>
#include <hip/hip_cooperative_groups.h>

namespace cg = cooperative_groups;

constexpr int kB = 64, kS = 2048, kD = 512, kL = 4;

// CONFIRMED (R15, 48-step bit-exact survival): XLA EmitFastTanh with_fma=true:
// clamp +-7.99881172180175781, FMA-contracted Horner rational, num/q division,
// tiny |x|<0.0004 passthrough of the unclamped input.
__device__ __forceinline__ float tanh_ref(float x0) {
#pragma clang fp contract(off)
  const float kMax = 7.99881172180175781f;
  float xc = fminf(fmaxf(x0, -kMax), kMax);
  float x2 = xc * xc;
  float p = -2.76076847742355e-16f;
  p = fmaf(x2, p, 2.00018790482477e-13f);
  p = fmaf(x2, p, -8.60467152213735e-11f);
  p = fmaf(x2, p, 5.12229709037114e-08f);
  p = fmaf(x2, p, 1.48572235717979e-05f);
  p = fmaf(x2, p, 6.37261928875436e-04f);
  p = fmaf(x2, p, 4.89352455891786e-03f);
  float num = xc * p;
  float q = 1.19825839466702e-06f;
  q = fmaf(x2, q, 1.18534705686654e-04f);
  q = fmaf(x2, q, 2.26843463243900e-03f);
  q = fmaf(x2, q, 4.89352518554385e-03f);
  float r = num / q;
  return (fabsf(x0) < 0.0004f) ? x0 : r;
}

// grid 256 = layer(4) x bgroup(8) x jgroup(8); block 256 = bq(4) x jlane(64).
// Thread: 2 batches x 1 column. Anti-diagonal wavestep w: cell (t=w-l, l).
// CONFIRMED GEMM arithmetic: per output, dw = single ascending-k FMA chain
// (k=0..511) over inp*W[k][j]; du likewise over hpr*U[k][j]; z=(dw+du)+bias.
__global__ __launch_bounds__(256, 1) void rnn_full(
    const float* __restrict__ x, const float* __restrict__ Wh,
    const float* __restrict__ Uh, const float* __restrict__ bias,
    float* __restrict__ out, float* __restrict__ ws) {
  cg::grid_group grid = cg::this_grid();
  float* Hbuf = ws;  // [2][L][B][D] f32 (1 MB)

  const int tid = threadIdx.x, bid = blockIdx.x;
  const int l  = bid >> 6;
  const int bg = (bid >> 3) & 7;  // 8 b-groups of 8
  const int jg = bid & 7;         // 8 j-groups of 64
  const int jl = tid & 63;
  const int bq = tid >> 6;        // 0..3 -> batch pair within group
  const int j  = jg * 64 + jl;
  const int b0 = bg * 8 + bq * 2;

  __shared__ float iS[8][512];
  __shared__ float hS[8][512];

  for (int i = bid * 256 + tid; i < 2 * kL * kB * kD; i += 256 * 256)
    Hbuf[i] = 0.f;
  grid.sync();

  const float* Wcol = Wh + (long)l * kD * kD + j;
  const float* Ucol = Uh + (long)l * kD * kD + j;
  const float bv = bias[l * kD + j];

  for (int w = 0; w < kS + kL - 1; ++w) {
    const int t = w - l;
    if (t >= 0 && t < kS) {
      const int cur = w & 1, prv = cur ^ 1;
      // ---- stage 8 inp rows + 8 h(t-1) rows into LDS ----
      const float* hbase =
          Hbuf + (((long)prv * kL + l) * kB + bg * 8) * (long)kD;
      const float* ibase =
          (l == 0) ? nullptr
                   : Hbuf + (((long)prv * kL + (l - 1)) * kB + bg * 8) * (long)kD;
      for (int i = tid; i < 8 * 128; i += 256) {
        const int r = i >> 7, q4 = (i & 127) * 4;
        const float* isrc = (l == 0)
            ? (x + ((long)(bg * 8 + r) * kS + t) * kD + q4)
            : (ibase + (long)r * kD + q4);
        *(float4*)&iS[r][q4] = *(const float4*)isrc;
        *(float4*)&hS[r][q4] = *(const float4*)(hbase + (long)r * kD + q4);
      }
      __syncthreads();

      // ---- 4 independent ascending-k FMA chains (confirmed order) ----
      const int r0 = bq * 2, r1 = r0 + 1;
      float dw0, dw1, du0, du1;
      {
#pragma clang fp contract(off)
        dw0 = 0.f; dw1 = 0.f; du0 = 0.f; du1 = 0.f;
#pragma unroll 4
        for (int k = 0; k < 512; ++k) {
          const float wv = Wcol[(long)k * kD];
          const float uv = Ucol[(long)k * kD];
          dw0 = fmaf(iS[r0][k], wv, dw0);
          dw1 = fmaf(iS[r1][k], wv, dw1);
          du0 = fmaf(hS[r0][k], uv, du0);
          du1 = fmaf(hS[r1][k], uv, du1);
        }
      }
      float z0, z1;
      {
#pragma clang fp contract(off)
        z0 = (dw0 + du0) + bv;
        z1 = (dw1 + du1) + bv;
      }
      const float h0 = tanh_ref(z0);
      const float h1 = tanh_ref(z1);

      float* ho = Hbuf + (((long)cur * kL + l) * kB) * (long)kD;
      ho[(long)b0 * kD + j] = h0;
      ho[(long)(b0 + 1) * kD + j] = h1;
      if (l == kL - 1) {
        out[((long)b0 * kS + t) * kD + j] = h0;
        out[((long)(b0 + 1) * kS + t) * kD + j] = h1;
      }
    }
    grid.sync();
  }
}

extern "C" void kernel_launch(void* const* d_in, const int* in_sizes, int n_in,
                              void* d_out, int out_size, void* d_ws, size_t ws_size,
                              hipStream_t stream) {
  const float* x    = (const float*)d_in[0];
  const float* Wh   = (const float*)d_in[1];
  const float* Uh   = (const float*)d_in[2];
  const float* bias = (const float*)d_in[3];
  float* out = (float*)d_out;
  float* ws  = (float*)d_ws;

  void* args[] = {(void*)&x, (void*)&Wh, (void*)&Uh, (void*)&bias,
                  (void*)&out, (void*)&ws};
  hipLaunchCooperativeKernel((void*)rnn_full, dim3(256), dim3(256), args, 0,
                             stream);
}